// Round 7
// baseline (381.880 us; speedup 1.0000x reference)
//
#include <hip/hip_runtime.h>

// TxModel: B=16384, K=64 tokens, DIN=49, D=16, NH=2, HD=8, FF=32
// R11: DUAL-BATCH blocks. Grid 8192; each block processes b0=2*bid and b0+1.
// Wave w owns M-tile w of BOTH batches; every phase runs both batches'
// independent chains in one scheduling region (2x in-wave ILP on the serial
// MFMA->exp2->epilogue and DPP-reduce chains). Shared loads (9 weight frags,
// ep, hbias - batch-independent) issued once per block instead of once per
// batch element; one barrier and one launch serve two batch elements.
// LDS duplicated per batch (+HALF), 21KB -> 7 blocks/CU.
// Carried: R10 DPP rotate-reduce LNs, R8 global->register x with remapped
// chunk2 weights + single barrier, R7 in-register P via swapped scores +
// slot-permuted V, folded biases in MFMA C-inputs, k pre-scaled,
// rcp/exp2/rsq natives, E[x^2]-E[x]^2 LNs.

#define SCALE 0.510069729f   // log2(e)/sqrt(8)

// LDS layout per batch half (short indices), HALF = 5256 shorts:
//   KR  [64][24] bf16 k rows (cols 16..23 zeroed)  [0,1536)
//   VTB [16][72] bf16 v^T, slot-permuted           [1536,2688)
//   HR  [64][40] bf16 h/q/ctx/hln/ff rows          [2688,5248)
//   RED 4 floats                                   [5248,5256)
#define KRS   24
#define VTB   1536
#define VTS   72
#define HRB   2688
#define HRS   40
#define RED   5248
#define HALF  5256
#define SMTOT 10512   // 21024 B -> 7 blocks/CU

// ws layout (floats): [0,2304) 9 weight B-frags (v8bf: frag*64+lane)
//                     [2304,3328) hbias [w][lane][r] = proj_b[c]+pos[tok][c]
//                     [3328,3584) epil  [c][16]   (ep[1] pre-scaled by SCALE)
#define WS_HB   2304
#define WS_EP   3328

typedef __bf16 v8bf __attribute__((ext_vector_type(8)));
typedef float  v4f  __attribute__((ext_vector_type(4)));

#define LDS_ORDER() __asm__ volatile("" ::: "memory")

static __device__ __forceinline__ short f2bs(float f) {
    __bf16 h = (__bf16)f;
    return __builtin_bit_cast(short, h);
}
#define MFMA(a,b,c) __builtin_amdgcn_mfma_f32_16x16x32_bf16((a),(b),(c),0,0,0)

// ds_swizzle, compile-time pattern. BitMode offset=(xor<<10)|(or<<5)|and.
template<int IMM> static __device__ __forceinline__ float swz(float x) {
    return __builtin_bit_cast(float,
        __builtin_amdgcn_ds_swizzle(__builtin_bit_cast(int, x), IMM));
}

// DPP-fused add. CTRL: 0xB1=quad_perm xor1, 0x4E=quad_perm xor2,
// 0x124=row_ror:4, 0x128=row_ror:8.
template<int CTRL> static __device__ __forceinline__ float dppadd(float v) {
    int t = __builtin_amdgcn_update_dpp(0, __builtin_bit_cast(int, v),
                                        CTRL, 0xF, 0xF, true);
    return v + __builtin_bit_cast(float, t);
}

// Sum over the 16 lanes of each row: quad butterfly then rotate-reduce.
static __device__ __forceinline__ void red16(v4f& v) {
    #pragma unroll
    for (int r = 0; r < 4; ++r) v[r] = dppadd<0xB1>(v[r]);
    #pragma unroll
    for (int r = 0; r < 4; ++r) v[r] = dppadd<0x4E>(v[r]);
    #pragma unroll
    for (int r = 0; r < 4; ++r) v[r] = dppadd<0x124>(v[r]);
    #pragma unroll
    for (int r = 0; r < 4; ++r) v[r] = dppadd<0x128>(v[r]);
}

__global__ __launch_bounds__(256)
void tx_prep(const float* __restrict__ proj_w, const float* __restrict__ proj_b,
             const float* __restrict__ pos,
             const float* __restrict__ in_proj_w, const float* __restrict__ in_proj_b,
             const float* __restrict__ out_w, const float* __restrict__ out_b,
             const float* __restrict__ ln1_g, const float* __restrict__ ln1_b,
             const float* __restrict__ lin1_w, const float* __restrict__ lin1_b,
             const float* __restrict__ lin2_w, const float* __restrict__ lin2_b,
             const float* __restrict__ ln2_g, const float* __restrict__ ln2_b,
             const float* __restrict__ head_w, float* __restrict__ ws)
{
    const int tid = threadIdx.x;
    const int wv = tid >> 6, lane = tid & 63;
    const int g = lane >> 4, c = lane & 15;
    v8bf* wf = (v8bf*)ws;
    v8bf F;
    if (wv == 0) {
        #pragma unroll
        for (int j = 0; j < 8; ++j) F[j] = (__bf16)proj_w[c*49 + g*8 + j];
        wf[0*64 + lane] = F;
        // remapped K-chunk2: g=0 -> k=32+j; g=1 -> k=40+j; g=2 -> only j==7
        // live (k=48); g=3 -> dead (A side loads col min(32+g*8,41)).
        #pragma unroll
        for (int j = 0; j < 8; ++j) {
            int k = (g == 0) ? (32 + j) : (g == 1) ? (40 + j)
                  : (g == 2 && j == 7) ? 48 : -1;
            F[j] = (k >= 0) ? (__bf16)proj_w[c*49 + k] : (__bf16)0.f;
        }
        wf[1*64 + lane] = F;
        #pragma unroll
        for (int nt = 0; nt < 3; ++nt) {
            #pragma unroll
            for (int j = 0; j < 8; ++j) { int k = g*8 + j; F[j] = (k < 16) ? (__bf16)in_proj_w[(nt*16 + c)*16 + k] : (__bf16)0.f; }
            wf[(2 + nt)*64 + lane] = F;
        }
    } else if (wv == 1) {
        #pragma unroll
        for (int j = 0; j < 8; ++j) { int k = g*8 + j; F[j] = (k < 16) ? (__bf16)out_w[c*16 + k] : (__bf16)0.f; }
        wf[5*64 + lane] = F;
        #pragma unroll
        for (int nt = 0; nt < 2; ++nt) {
            #pragma unroll
            for (int j = 0; j < 8; ++j) { int k = g*8 + j; F[j] = (k < 16) ? (__bf16)lin1_w[(nt*16 + c)*16 + k] : (__bf16)0.f; }
            wf[(6 + nt)*64 + lane] = F;
        }
        #pragma unroll
        for (int j = 0; j < 8; ++j) F[j] = (__bf16)lin2_w[c*32 + g*8 + j];
        wf[8*64 + lane] = F;
        if (lane < 16) {
            float* ep = ws + WS_EP + lane*16;
            ep[0]  = in_proj_b[lane];              // q bias
            ep[1]  = in_proj_b[16 + lane] * SCALE; // k bias, pre-scaled
            ep[2]  = in_proj_b[32 + lane];         // v bias
            ep[3]  = out_b[lane];
            ep[4]  = ln1_g[lane];
            ep[5]  = ln1_b[lane];
            ep[6]  = lin1_b[lane];
            ep[7]  = lin1_b[16 + lane];
            ep[8]  = lin2_b[lane];
            ep[9]  = ln2_g[lane];
            ep[10] = ln2_b[lane];
            ep[11] = head_w[lane];
            ep[12] = 0.f; ep[13] = 0.f; ep[14] = 0.f; ep[15] = 0.f;
        }
    } else {
        // hbias: [w][lane][r]; waves 2,3 take ww = {0,1} / {2,3}
        float* hb = ws + WS_HB;
        const int w0 = (wv - 2) * 2;
        #pragma unroll
        for (int i = 0; i < 2; ++i) {
            int ww = w0 + i;
            #pragma unroll
            for (int r = 0; r < 4; ++r)
                hb[ww*256 + lane*4 + r] = proj_b[c] + pos[(ww*16 + g*4 + r)*16 + c];
        }
    }
}

__global__ __launch_bounds__(256, 6)
void tx_main(const float* __restrict__ x, const float* __restrict__ ws,
             const float* __restrict__ head_b, float* __restrict__ out)
{
    __shared__ __align__(16) short sm[SMTOT];
    const int tid   = threadIdx.x;
    const int w     = tid >> 6;
    const int lane  = tid & 63;
    const int g     = lane >> 4;
    const int c     = lane & 15;
    const int b0    = blockIdx.x * 2;
    const int myrow = w*16 + c;
    const int tok0  = w*16 + g*4;
    const v8bf* wf  = (const v8bf*)ws;
    const float4* ep4 = (const float4*)(ws + WS_EP);

    v8bf zfrag;
    #pragma unroll
    for (int j = 0; j < 8; ++j) zfrag[j] = (__bf16)0.f;
    const v4f zacc = {0.f, 0.f, 0.f, 0.f};

    // ---- zero pads, both halves ----
    *(unsigned long long*)&sm[HRB + myrow*HRS + 16 + g*4] = 0ull;
    *(unsigned long long*)&sm[HALF + HRB + myrow*HRS + 16 + g*4] = 0ull;
    if (lane < 16) {
        float4 z4 = {0.f, 0.f, 0.f, 0.f};
        *(float4*)&sm[(w*16 + lane)*KRS + 16] = z4;
        *(float4*)&sm[HALF + (w*16 + lane)*KRS + 16] = z4;
    }

    // ---- proj: h = x @ proj_w^T, x global->register, both batches ----
    v4f hC0, hC1;
    {
        const float* xr0 = x + (size_t)b0 * 3136 + myrow*49;
        const float* xr1 = xr0 + 3136;
        int off1 = 32 + g*8; if (off1 > 41) off1 = 41;   // bounds-safe chunk2
        v8bf a00, a01, a10, a11;
        #pragma unroll
        for (int j = 0; j < 8; ++j) a00[j] = (__bf16)xr0[g*8 + j];
        #pragma unroll
        for (int j = 0; j < 8; ++j) a01[j] = (__bf16)xr0[off1 + j];
        #pragma unroll
        for (int j = 0; j < 8; ++j) a10[j] = (__bf16)xr1[g*8 + j];
        #pragma unroll
        for (int j = 0; j < 8; ++j) a11[j] = (__bf16)xr1[off1 + j];
        v4f hb = ((const v4f*)(ws + WS_HB))[w*64 + lane];   // shared
        v8bf Bp0 = wf[0*64 + lane], Bp1 = wf[1*64 + lane];  // shared
        hC0 = MFMA(a00, Bp0, hb);
        hC1 = MFMA(a10, Bp0, hb);
        hC0 = MFMA(a01, Bp1, hC0);
        hC1 = MFMA(a11, Bp1, hC1);
        #pragma unroll
        for (int r = 0; r < 4; ++r) {
            sm[HRB + (tok0 + r)*HRS + c]        = f2bs(hC0[r]);
            sm[HALF + HRB + (tok0 + r)*HRS + c] = f2bs(hC1[r]);
        }
    }
    LDS_ORDER();   // h write -> qkv read is wave-local

    // ---- qkv = h @ in_proj_w^T + b; v SLOT-PERMUTED; both batches ----
    {
        v8bf aA = *(const v8bf*)&sm[HRB + myrow*HRS + g*8];
        v8bf aB = *(const v8bf*)&sm[HALF + HRB + myrow*HRS + g*8];
        v8bf Bq0 = wf[2*64 + lane], Bq1 = wf[3*64 + lane], Bq2 = wf[4*64 + lane];
        v4f qC0 = MFMA(aA, Bq0, zacc);
        v4f qC1 = MFMA(aB, Bq0, zacc);
        v4f kC0 = MFMA(aA, Bq1, zacc);
        v4f kC1 = MFMA(aB, Bq1, zacc);
        v4f vC0 = MFMA(aA, Bq2, zacc);
        v4f vC1 = MFMA(aB, Bq2, zacc);
        float4 e0 = ep4[c*4];
        const int vsl = VTB + c*VTS + 32*(w >> 1) + 8*g + 4*(w & 1);
        #pragma unroll
        for (int r = 0; r < 4; ++r) {
            int tok = tok0 + r;
            sm[HRB + tok*HRS + c]        = f2bs(qC0[r] + e0.x);
            sm[HALF + HRB + tok*HRS + c] = f2bs(qC1[r] + e0.x);
            sm[tok*KRS + c]              = f2bs(fmaf(kC0[r], SCALE, e0.y));
            sm[HALF + tok*KRS + c]       = f2bs(fmaf(kC1[r], SCALE, e0.y));
            sm[vsl + r]                  = f2bs(vC0[r] + e0.z);
            sm[HALF + vsl + r]           = f2bs(vC1[r] + e0.z);
        }
    }
    __syncthreads();   // the ONE barrier: k/V/KR-zero cross-wave visibility

    // ---- attention: swapped scores -> P in-register -> PV; both batches ----
    v4f ctx00, ctx01, ctx10, ctx11;   // [batch][head]
    {
        v8bf aq0 = *(const v8bf*)&sm[HRB + myrow*HRS + g*8];
        v8bf aq1 = *(const v8bf*)&sm[HALF + HRB + myrow*HRS + g*8];
        #pragma unroll
        for (int hh = 0; hh < 2; ++hh) {
            v8bf bq0 = (g == hh) ? aq0 : zfrag;
            v8bf bq1 = (g == hh) ? aq1 : zfrag;
            v8bf plo0, phi0, plo1, phi1;
            {
                v8bf k0 = *(const v8bf*)&sm[(0*16 + c)*KRS + g*8];
                v8bf k1 = *(const v8bf*)&sm[(1*16 + c)*KRS + g*8];
                v8bf k2 = *(const v8bf*)&sm[(2*16 + c)*KRS + g*8];
                v8bf k3 = *(const v8bf*)&sm[(3*16 + c)*KRS + g*8];
                v4f s0 = MFMA(k0, bq0, zacc);
                v4f s1 = MFMA(k1, bq0, zacc);
                v4f s2 = MFMA(k2, bq0, zacc);
                v4f s3 = MFMA(k3, bq0, zacc);
                #pragma unroll
                for (int r = 0; r < 4; ++r) {
                    plo0[r]     = (__bf16)__builtin_amdgcn_exp2f(s0[r]);
                    plo0[4 + r] = (__bf16)__builtin_amdgcn_exp2f(s1[r]);
                    phi0[r]     = (__bf16)__builtin_amdgcn_exp2f(s2[r]);
                    phi0[4 + r] = (__bf16)__builtin_amdgcn_exp2f(s3[r]);
                }
                v8bf m0 = *(const v8bf*)&sm[HALF + (0*16 + c)*KRS + g*8];
                v8bf m1 = *(const v8bf*)&sm[HALF + (1*16 + c)*KRS + g*8];
                v8bf m2 = *(const v8bf*)&sm[HALF + (2*16 + c)*KRS + g*8];
                v8bf m3 = *(const v8bf*)&sm[HALF + (3*16 + c)*KRS + g*8];
                v4f t0 = MFMA(m0, bq1, zacc);
                v4f t1 = MFMA(m1, bq1, zacc);
                v4f t2 = MFMA(m2, bq1, zacc);
                v4f t3 = MFMA(m3, bq1, zacc);
                #pragma unroll
                for (int r = 0; r < 4; ++r) {
                    plo1[r]     = (__bf16)__builtin_amdgcn_exp2f(t0[r]);
                    plo1[4 + r] = (__bf16)__builtin_amdgcn_exp2f(t1[r]);
                    phi1[r]     = (__bf16)__builtin_amdgcn_exp2f(t2[r]);
                    phi1[4 + r] = (__bf16)__builtin_amdgcn_exp2f(t3[r]);
                }
            }
            // V (slot-permuted) + ones column for softmax denominator
            v8bf bv00 = zfrag, bv10 = zfrag, bv01 = zfrag, bv11 = zfrag;
            bool act  = (hh == 0) ? (c < 8) : (c >= 8);
            int  onec = (hh == 0) ? 8 : 7;
            if (act) {
                bv00 = *(const v8bf*)&sm[VTB + c*VTS + g*8];
                bv10 = *(const v8bf*)&sm[VTB + c*VTS + 32 + g*8];
                bv01 = *(const v8bf*)&sm[HALF + VTB + c*VTS + g*8];
                bv11 = *(const v8bf*)&sm[HALF + VTB + c*VTS + 32 + g*8];
            } else if (c == onec) {
                #pragma unroll
                for (int j = 0; j < 8; ++j) {
                    bv00[j] = (__bf16)1.f; bv10[j] = (__bf16)1.f;
                    bv01[j] = (__bf16)1.f; bv11[j] = (__bf16)1.f;
                }
            }
            v4f a0 = MFMA(plo0, bv00, zacc);
            a0 = MFMA(phi0, bv10, a0);
            v4f a1 = MFMA(plo1, bv01, zacc);
            a1 = MFMA(phi1, bv11, a1);
            if (hh) { ctx01 = a0; ctx11 = a1; }
            else    { ctx00 = a0; ctx10 = a1; }
        }
    }

    // ---- softmax normalize, both batches ----
    {
        #pragma unroll
        for (int r = 0; r < 4; ++r) {
            float l00 = swz<0x110>(ctx00[r]);   // from lane (lane&48)|8
            float l01 = swz<0x0F0>(ctx01[r]);   // from lane (lane&48)|7
            float l10 = swz<0x110>(ctx10[r]);
            float l11 = swz<0x0F0>(ctx11[r]);
            float n0 = (c < 8) ? ctx00[r] : ctx01[r];
            float d0 = (c < 8) ? l00 : l01;
            float n1 = (c < 8) ? ctx10[r] : ctx11[r];
            float d1 = (c < 8) ? l10 : l11;
            sm[HRB + (tok0 + r)*HRS + c]        = f2bs(n0 * __builtin_amdgcn_rcpf(d0));
            sm[HALF + HRB + (tok0 + r)*HRS + c] = f2bs(n1 * __builtin_amdgcn_rcpf(d1));
        }
    }
    LDS_ORDER();

    // ---- out-proj (+hC via C-input) + LN1 (DPP reduce), both batches ----
    v4f hln0, hln1;
    {
        v8bf aA = *(const v8bf*)&sm[HRB + myrow*HRS + g*8];
        v8bf aB = *(const v8bf*)&sm[HALF + HRB + myrow*HRS + g*8];
        v8bf Bo = wf[5*64 + lane];
        v4f oC0 = MFMA(aA, Bo, hC0);
        v4f oC1 = MFMA(aB, Bo, hC1);
        float4 e0 = ep4[c*4];
        float4 e1 = ep4[c*4 + 1];
        v4f hn0, s0, q0, hn1, s1, q1;
        #pragma unroll
        for (int r = 0; r < 4; ++r) {
            hn0[r] = oC0[r] + e0.w; s0[r] = hn0[r]; q0[r] = hn0[r]*hn0[r];
            hn1[r] = oC1[r] + e0.w; s1[r] = hn1[r]; q1[r] = hn1[r]*hn1[r];
        }
        red16(s0); red16(q0); red16(s1); red16(q1);
        #pragma unroll
        for (int r = 0; r < 4; ++r) {
            float m0 = s0[r]*0.0625f;
            float i0 = __builtin_amdgcn_rsqf(fmaf(q0[r], 0.0625f, fmaf(m0, -m0, 1e-5f)));
            hln0[r] = (hn0[r] - m0)*i0*e1.x + e1.y;
            sm[HRB + (tok0 + r)*HRS + c] = f2bs(hln0[r]);
            float m1 = s1[r]*0.0625f;
            float i1 = __builtin_amdgcn_rsqf(fmaf(q1[r], 0.0625f, fmaf(m1, -m1, 1e-5f)));
            hln1[r] = (hn1[r] - m1)*i1*e1.x + e1.y;
            sm[HALF + HRB + (tok0 + r)*HRS + c] = f2bs(hln1[r]);
        }
    }
    LDS_ORDER();

    // ---- FFN: lin1(+bias,relu) -> lin2 (hln folded into C), both ----
    v4f o20, o21;
    {
        v8bf aA = *(const v8bf*)&sm[HRB + myrow*HRS + g*8];
        v8bf aB = *(const v8bf*)&sm[HALF + HRB + myrow*HRS + g*8];
        v8bf Bl10 = wf[6*64 + lane], Bl11 = wf[7*64 + lane];
        v4f f00 = MFMA(aA, Bl10, zacc);
        v4f f01 = MFMA(aA, Bl11, zacc);
        v4f f10 = MFMA(aB, Bl10, zacc);
        v4f f11 = MFMA(aB, Bl11, zacc);
        float4 e1 = ep4[c*4 + 1];
        #pragma unroll
        for (int r = 0; r < 4; ++r) {
            int tok = tok0 + r;
            sm[HRB + tok*HRS + c]             = f2bs(fmaxf(f00[r] + e1.z, 0.f));
            sm[HRB + tok*HRS + 16 + c]        = f2bs(fmaxf(f01[r] + e1.w, 0.f));
            sm[HALF + HRB + tok*HRS + c]      = f2bs(fmaxf(f10[r] + e1.z, 0.f));
            sm[HALF + HRB + tok*HRS + 16 + c] = f2bs(fmaxf(f11[r] + e1.w, 0.f));
        }
        LDS_ORDER();
        v8bf Bl2 = wf[8*64 + lane];
        v8bf a2A = *(const v8bf*)&sm[HRB + myrow*HRS + g*8];
        v8bf a2B = *(const v8bf*)&sm[HALF + HRB + myrow*HRS + g*8];
        o20 = MFMA(a2A, Bl2, hln0);
        o21 = MFMA(a2B, Bl2, hln1);
    }

    // ---- +lin2_b, LN2 (DPP), head dot; both batches ----
    float part0 = 0.f, part1 = 0.f;
    {
        float4 e2 = ep4[c*4 + 2];
        v4f hn0, s0, q0, hn1, s1, q1;
        #pragma unroll
        for (int r = 0; r < 4; ++r) {
            hn0[r] = o20[r] + e2.x; s0[r] = hn0[r]; q0[r] = hn0[r]*hn0[r];
            hn1[r] = o21[r] + e2.x; s1[r] = hn1[r]; q1[r] = hn1[r]*hn1[r];
        }
        red16(s0); red16(q0); red16(s1); red16(q1);
        #pragma unroll
        for (int r = 0; r < 4; ++r) {
            float m0 = s0[r]*0.0625f;
            float i0 = __builtin_amdgcn_rsqf(fmaf(q0[r], 0.0625f, fmaf(m0, -m0, 1e-5f)));
            part0 = fmaf((hn0[r] - m0)*i0*e2.y + e2.z, e2.w, part0);
            float m1 = s1[r]*0.0625f;
            float i1 = __builtin_amdgcn_rsqf(fmaf(q1[r], 0.0625f, fmaf(m1, -m1, 1e-5f)));
            part1 = fmaf((hn1[r] - m1)*i1*e2.y + e2.z, e2.w, part1);
        }
    }
    // 64-lane sums: DPP within 16, xor16, cross-32; two independent chains
    part0 = dppadd<0xB1>(part0);  part1 = dppadd<0xB1>(part1);
    part0 = dppadd<0x4E>(part0);  part1 = dppadd<0x4E>(part1);
    part0 = dppadd<0x124>(part0); part1 = dppadd<0x124>(part1);
    part0 = dppadd<0x128>(part0); part1 = dppadd<0x128>(part1);
    part0 += swz<0x401F>(part0);  part1 += swz<0x401F>(part1);
    part0 += __shfl_xor(part0, 32, 64);
    part1 += __shfl_xor(part1, 32, 64);
    float* fr0 = (float*)&sm[RED];
    float* fr1 = (float*)&sm[HALF + RED];
    if (lane == 0) { fr0[w] = part0; fr1[w] = part1; }
    __syncthreads();
    if (tid < 2) {
        const float* fr = (tid == 0) ? fr0 : fr1;
        out[b0 + tid] = (fr[0] + fr[1] + fr[2] + fr[3]) * (1.f/64.f) + head_b[0];
    }
}

extern "C" void kernel_launch(void* const* d_in, const int* in_sizes, int n_in,
                              void* d_out, int out_size, void* d_ws, size_t ws_size,
                              hipStream_t stream) {
    const float* x         = (const float*)d_in[0];
    const float* proj_w    = (const float*)d_in[1];
    const float* proj_b    = (const float*)d_in[2];
    const float* pos       = (const float*)d_in[3];
    const float* in_proj_w = (const float*)d_in[4];
    const float* in_proj_b = (const float*)d_in[5];
    const float* out_w     = (const float*)d_in[6];
    const float* out_b     = (const float*)d_in[7];
    const float* ln1_g     = (const float*)d_in[8];
    const float* ln1_b     = (const float*)d_in[9];
    const float* lin1_w    = (const float*)d_in[10];
    const float* lin1_b    = (const float*)d_in[11];
    const float* lin2_w    = (const float*)d_in[12];
    const float* lin2_b    = (const float*)d_in[13];
    const float* ln2_g     = (const float*)d_in[14];
    const float* ln2_b     = (const float*)d_in[15];
    const float* head_w    = (const float*)d_in[16];
    const float* head_b    = (const float*)d_in[17];
    float* ws = (float*)d_ws;

    tx_prep<<<1, 256, 0, stream>>>(proj_w, proj_b, pos, in_proj_w, in_proj_b,
                                   out_w, out_b, ln1_g, ln1_b, lin1_w, lin1_b,
                                   lin2_w, lin2_b, ln2_g, ln2_b, head_w, ws);
    tx_main<<<8192, 256, 0, stream>>>(x, ws, head_b, (float*)d_out);
}

// Round 8
// 318.597 us; speedup vs baseline: 1.1986x; 1.1986x over previous
//
#include <hip/hip_runtime.h>

// TxModel: B=16384, K=64 tokens, DIN=49, D=16, NH=2, HD=8, FF=32
// R12: dual-batch with SEQUENTIAL attention (fixes R11's register spill).
// R11 post-mortem: WRITE_SIZE 0.5MB->262MB = scratch spill (full dual-batch
// attention needs ~150 live VGPRs vs the 85 cap). R12 keeps dual-batch for
// proj/qkv/LN1/FFN/LN2 (small live state, shared weight loads, 2x ILP on the
// serial DPP/MFMA chains) but runs attention+normalize per batch serially:
// peak live ~= single-batch + hC1 (~80 VGPR) -> no spill. K-frags hoisted
// across the two heads; exp-cvt tightly paired (s0,s1->plo before s2,s3) to
// cap transients. launch_bounds(256,6): cap 85 VGPR, 6 blocks/CU (LDS 21KB).
// Carried: R10 DPP rotate-reduce LNs, R8 global->register x + single barrier,
// R7 in-register P via swapped scores + slot-permuted V, folded biases in
// MFMA C-inputs, k pre-scaled, rcp/exp2/rsq natives, E[x^2]-E[x]^2 LNs.

#define SCALE 0.510069729f   // log2(e)/sqrt(8)

// LDS layout per batch half (short indices), HALF = 5256 shorts:
//   KR  [64][24] bf16 k rows (cols 16..23 zeroed)  [0,1536)
//   VTB [16][72] bf16 v^T, slot-permuted           [1536,2688)
//   HR  [64][40] bf16 h/q/ctx/hln/ff rows          [2688,5248)
//   RED 4 floats                                   [5248,5256)
#define KRS   24
#define VTB   1536
#define VTS   72
#define HRB   2688
#define HRS   40
#define RED   5248
#define HALF  5256
#define SMTOT 10512   // 21024 B

// ws layout (floats): [0,2304) 9 weight B-frags (v8bf: frag*64+lane)
//                     [2304,3328) hbias [w][lane][r] = proj_b[c]+pos[tok][c]
//                     [3328,3584) epil  [c][16]   (ep[1] pre-scaled by SCALE)
#define WS_HB   2304
#define WS_EP   3328

typedef __bf16 v8bf __attribute__((ext_vector_type(8)));
typedef float  v4f  __attribute__((ext_vector_type(4)));

#define LDS_ORDER() __asm__ volatile("" ::: "memory")

static __device__ __forceinline__ short f2bs(float f) {
    __bf16 h = (__bf16)f;
    return __builtin_bit_cast(short, h);
}
#define MFMA(a,b,c) __builtin_amdgcn_mfma_f32_16x16x32_bf16((a),(b),(c),0,0,0)

// ds_swizzle, compile-time pattern. BitMode offset=(xor<<10)|(or<<5)|and.
template<int IMM> static __device__ __forceinline__ float swz(float x) {
    return __builtin_bit_cast(float,
        __builtin_amdgcn_ds_swizzle(__builtin_bit_cast(int, x), IMM));
}

// DPP-fused add. CTRL: 0xB1=quad_perm xor1, 0x4E=quad_perm xor2,
// 0x124=row_ror:4, 0x128=row_ror:8.
template<int CTRL> static __device__ __forceinline__ float dppadd(float v) {
    int t = __builtin_amdgcn_update_dpp(0, __builtin_bit_cast(int, v),
                                        CTRL, 0xF, 0xF, true);
    return v + __builtin_bit_cast(float, t);
}

// Sum over the 16 lanes of each row: quad butterfly then rotate-reduce.
static __device__ __forceinline__ void red16(v4f& v) {
    #pragma unroll
    for (int r = 0; r < 4; ++r) v[r] = dppadd<0xB1>(v[r]);
    #pragma unroll
    for (int r = 0; r < 4; ++r) v[r] = dppadd<0x4E>(v[r]);
    #pragma unroll
    for (int r = 0; r < 4; ++r) v[r] = dppadd<0x124>(v[r]);
    #pragma unroll
    for (int r = 0; r < 4; ++r) v[r] = dppadd<0x128>(v[r]);
}

__global__ __launch_bounds__(256)
void tx_prep(const float* __restrict__ proj_w, const float* __restrict__ proj_b,
             const float* __restrict__ pos,
             const float* __restrict__ in_proj_w, const float* __restrict__ in_proj_b,
             const float* __restrict__ out_w, const float* __restrict__ out_b,
             const float* __restrict__ ln1_g, const float* __restrict__ ln1_b,
             const float* __restrict__ lin1_w, const float* __restrict__ lin1_b,
             const float* __restrict__ lin2_w, const float* __restrict__ lin2_b,
             const float* __restrict__ ln2_g, const float* __restrict__ ln2_b,
             const float* __restrict__ head_w, float* __restrict__ ws)
{
    const int tid = threadIdx.x;
    const int wv = tid >> 6, lane = tid & 63;
    const int g = lane >> 4, c = lane & 15;
    v8bf* wf = (v8bf*)ws;
    v8bf F;
    if (wv == 0) {
        #pragma unroll
        for (int j = 0; j < 8; ++j) F[j] = (__bf16)proj_w[c*49 + g*8 + j];
        wf[0*64 + lane] = F;
        // remapped K-chunk2: g=0 -> k=32+j; g=1 -> k=40+j; g=2 -> only j==7
        // live (k=48); g=3 -> dead (A side loads col min(32+g*8,41)).
        #pragma unroll
        for (int j = 0; j < 8; ++j) {
            int k = (g == 0) ? (32 + j) : (g == 1) ? (40 + j)
                  : (g == 2 && j == 7) ? 48 : -1;
            F[j] = (k >= 0) ? (__bf16)proj_w[c*49 + k] : (__bf16)0.f;
        }
        wf[1*64 + lane] = F;
        #pragma unroll
        for (int nt = 0; nt < 3; ++nt) {
            #pragma unroll
            for (int j = 0; j < 8; ++j) { int k = g*8 + j; F[j] = (k < 16) ? (__bf16)in_proj_w[(nt*16 + c)*16 + k] : (__bf16)0.f; }
            wf[(2 + nt)*64 + lane] = F;
        }
    } else if (wv == 1) {
        #pragma unroll
        for (int j = 0; j < 8; ++j) { int k = g*8 + j; F[j] = (k < 16) ? (__bf16)out_w[c*16 + k] : (__bf16)0.f; }
        wf[5*64 + lane] = F;
        #pragma unroll
        for (int nt = 0; nt < 2; ++nt) {
            #pragma unroll
            for (int j = 0; j < 8; ++j) { int k = g*8 + j; F[j] = (k < 16) ? (__bf16)lin1_w[(nt*16 + c)*16 + k] : (__bf16)0.f; }
            wf[(6 + nt)*64 + lane] = F;
        }
        #pragma unroll
        for (int j = 0; j < 8; ++j) F[j] = (__bf16)lin2_w[c*32 + g*8 + j];
        wf[8*64 + lane] = F;
        if (lane < 16) {
            float* ep = ws + WS_EP + lane*16;
            ep[0]  = in_proj_b[lane];              // q bias
            ep[1]  = in_proj_b[16 + lane] * SCALE; // k bias, pre-scaled
            ep[2]  = in_proj_b[32 + lane];         // v bias
            ep[3]  = out_b[lane];
            ep[4]  = ln1_g[lane];
            ep[5]  = ln1_b[lane];
            ep[6]  = lin1_b[lane];
            ep[7]  = lin1_b[16 + lane];
            ep[8]  = lin2_b[lane];
            ep[9]  = ln2_g[lane];
            ep[10] = ln2_b[lane];
            ep[11] = head_w[lane];
            ep[12] = 0.f; ep[13] = 0.f; ep[14] = 0.f; ep[15] = 0.f;
        }
    } else {
        // hbias: [w][lane][r]; waves 2,3 take ww = {0,1} / {2,3}
        float* hb = ws + WS_HB;
        const int w0 = (wv - 2) * 2;
        #pragma unroll
        for (int i = 0; i < 2; ++i) {
            int ww = w0 + i;
            #pragma unroll
            for (int r = 0; r < 4; ++r)
                hb[ww*256 + lane*4 + r] = proj_b[c] + pos[(ww*16 + g*4 + r)*16 + c];
        }
    }
}

__global__ __launch_bounds__(256, 6)
void tx_main(const float* __restrict__ x, const float* __restrict__ ws,
             const float* __restrict__ head_b, float* __restrict__ out)
{
    __shared__ __align__(16) short sm[SMTOT];
    const int tid   = threadIdx.x;
    const int w     = tid >> 6;
    const int lane  = tid & 63;
    const int g     = lane >> 4;
    const int c     = lane & 15;
    const int b0    = blockIdx.x * 2;
    const int myrow = w*16 + c;
    const int tok0  = w*16 + g*4;
    const v8bf* wf  = (const v8bf*)ws;
    const float4* ep4 = (const float4*)(ws + WS_EP);

    v8bf zfrag;
    #pragma unroll
    for (int j = 0; j < 8; ++j) zfrag[j] = (__bf16)0.f;
    const v4f zacc = {0.f, 0.f, 0.f, 0.f};

    // ---- zero pads, both halves ----
    *(unsigned long long*)&sm[HRB + myrow*HRS + 16 + g*4] = 0ull;
    *(unsigned long long*)&sm[HALF + HRB + myrow*HRS + 16 + g*4] = 0ull;
    if (lane < 16) {
        float4 z4 = {0.f, 0.f, 0.f, 0.f};
        *(float4*)&sm[(w*16 + lane)*KRS + 16] = z4;
        *(float4*)&sm[HALF + (w*16 + lane)*KRS + 16] = z4;
    }

    // ---- proj: h = x @ proj_w^T, x global->register, both batches ----
    v4f hC0, hC1;
    {
        const float* xr0 = x + (size_t)b0 * 3136 + myrow*49;
        const float* xr1 = xr0 + 3136;
        int off1 = 32 + g*8; if (off1 > 41) off1 = 41;   // bounds-safe chunk2
        v8bf a00, a01, a10, a11;
        #pragma unroll
        for (int j = 0; j < 8; ++j) a00[j] = (__bf16)xr0[g*8 + j];
        #pragma unroll
        for (int j = 0; j < 8; ++j) a01[j] = (__bf16)xr0[off1 + j];
        #pragma unroll
        for (int j = 0; j < 8; ++j) a10[j] = (__bf16)xr1[g*8 + j];
        #pragma unroll
        for (int j = 0; j < 8; ++j) a11[j] = (__bf16)xr1[off1 + j];
        v4f hb = ((const v4f*)(ws + WS_HB))[w*64 + lane];   // shared
        v8bf Bp0 = wf[0*64 + lane], Bp1 = wf[1*64 + lane];  // shared
        hC0 = MFMA(a00, Bp0, hb);
        hC1 = MFMA(a10, Bp0, hb);
        hC0 = MFMA(a01, Bp1, hC0);
        hC1 = MFMA(a11, Bp1, hC1);
        #pragma unroll
        for (int r = 0; r < 4; ++r) {
            sm[HRB + (tok0 + r)*HRS + c]        = f2bs(hC0[r]);
            sm[HALF + HRB + (tok0 + r)*HRS + c] = f2bs(hC1[r]);
        }
    }
    LDS_ORDER();   // h write -> qkv read is wave-local

    // ---- qkv = h @ in_proj_w^T + b; v SLOT-PERMUTED; both batches ----
    {
        v8bf aA = *(const v8bf*)&sm[HRB + myrow*HRS + g*8];
        v8bf aB = *(const v8bf*)&sm[HALF + HRB + myrow*HRS + g*8];
        v8bf Bq0 = wf[2*64 + lane], Bq1 = wf[3*64 + lane], Bq2 = wf[4*64 + lane];
        v4f qC0 = MFMA(aA, Bq0, zacc);
        v4f qC1 = MFMA(aB, Bq0, zacc);
        v4f kC0 = MFMA(aA, Bq1, zacc);
        v4f kC1 = MFMA(aB, Bq1, zacc);
        v4f vC0 = MFMA(aA, Bq2, zacc);
        v4f vC1 = MFMA(aB, Bq2, zacc);
        float4 e0 = ep4[c*4];
        const int vsl = VTB + c*VTS + 32*(w >> 1) + 8*g + 4*(w & 1);
        #pragma unroll
        for (int r = 0; r < 4; ++r) {
            int tok = tok0 + r;
            sm[HRB + tok*HRS + c]        = f2bs(qC0[r] + e0.x);
            sm[HALF + HRB + tok*HRS + c] = f2bs(qC1[r] + e0.x);
            sm[tok*KRS + c]              = f2bs(fmaf(kC0[r], SCALE, e0.y));
            sm[HALF + tok*KRS + c]       = f2bs(fmaf(kC1[r], SCALE, e0.y));
            sm[vsl + r]                  = f2bs(vC0[r] + e0.z);
            sm[HALF + vsl + r]           = f2bs(vC1[r] + e0.z);
        }
    }
    __syncthreads();   // the ONE barrier: k/V/KR-zero cross-wave visibility

    // ---- attention, SEQUENTIAL per batch (caps live VGPRs; R11 spilled) ----
    #pragma unroll
    for (int bb = 0; bb < 2; ++bb) {
        const int B = bb ? HALF : 0;
        v4f ctxA, ctxB;   // head0 / head1
        {
            v8bf aq = *(const v8bf*)&sm[B + HRB + myrow*HRS + g*8];
            v8bf k0 = *(const v8bf*)&sm[B + (0*16 + c)*KRS + g*8];
            v8bf k1 = *(const v8bf*)&sm[B + (1*16 + c)*KRS + g*8];
            v8bf k2 = *(const v8bf*)&sm[B + (2*16 + c)*KRS + g*8];
            v8bf k3 = *(const v8bf*)&sm[B + (3*16 + c)*KRS + g*8];
            #pragma unroll
            for (int hh = 0; hh < 2; ++hh) {
                v8bf bq = (g == hh) ? aq : zfrag;
                v8bf plo, phi;
                {
                    v4f s0 = MFMA(k0, bq, zacc);
                    v4f s1 = MFMA(k1, bq, zacc);
                    #pragma unroll
                    for (int r = 0; r < 4; ++r) {
                        plo[r]     = (__bf16)__builtin_amdgcn_exp2f(s0[r]);
                        plo[4 + r] = (__bf16)__builtin_amdgcn_exp2f(s1[r]);
                    }
                    v4f s2 = MFMA(k2, bq, zacc);
                    v4f s3 = MFMA(k3, bq, zacc);
                    #pragma unroll
                    for (int r = 0; r < 4; ++r) {
                        phi[r]     = (__bf16)__builtin_amdgcn_exp2f(s2[r]);
                        phi[4 + r] = (__bf16)__builtin_amdgcn_exp2f(s3[r]);
                    }
                }
                // V (slot-permuted) + ones column for softmax denominator
                v8bf bv0 = zfrag, bv1 = zfrag;
                bool act  = (hh == 0) ? (c < 8) : (c >= 8);
                int  onec = (hh == 0) ? 8 : 7;
                if (act) {
                    bv0 = *(const v8bf*)&sm[B + VTB + c*VTS + g*8];
                    bv1 = *(const v8bf*)&sm[B + VTB + c*VTS + 32 + g*8];
                } else if (c == onec) {
                    #pragma unroll
                    for (int j = 0; j < 8; ++j) { bv0[j] = (__bf16)1.f; bv1[j] = (__bf16)1.f; }
                }
                v4f acc = MFMA(plo, bv0, zacc);
                acc = MFMA(phi, bv1, acc);
                if (hh) ctxB = acc; else ctxA = acc;
            }
        }
        // softmax normalize (l broadcast via ds_swizzle; v_rcp not div)
        #pragma unroll
        for (int r = 0; r < 4; ++r) {
            float l0 = swz<0x110>(ctxA[r]);   // from lane (lane&48)|8
            float l1 = swz<0x0F0>(ctxB[r]);   // from lane (lane&48)|7
            float num = (c < 8) ? ctxA[r] : ctxB[r];
            float den = (c < 8) ? l0 : l1;
            sm[B + HRB + (tok0 + r)*HRS + c] = f2bs(num * __builtin_amdgcn_rcpf(den));
        }
    }
    LDS_ORDER();

    // ---- out-proj (+hC via C-input) + LN1 (DPP reduce), both batches ----
    v4f hln0, hln1;
    {
        v8bf aA = *(const v8bf*)&sm[HRB + myrow*HRS + g*8];
        v8bf aB = *(const v8bf*)&sm[HALF + HRB + myrow*HRS + g*8];
        v8bf Bo = wf[5*64 + lane];
        v4f oC0 = MFMA(aA, Bo, hC0);
        v4f oC1 = MFMA(aB, Bo, hC1);
        float4 e0 = ep4[c*4];
        float4 e1 = ep4[c*4 + 1];
        v4f hn0, s0, q0, hn1, s1, q1;
        #pragma unroll
        for (int r = 0; r < 4; ++r) {
            hn0[r] = oC0[r] + e0.w; s0[r] = hn0[r]; q0[r] = hn0[r]*hn0[r];
            hn1[r] = oC1[r] + e0.w; s1[r] = hn1[r]; q1[r] = hn1[r]*hn1[r];
        }
        red16(s0); red16(q0); red16(s1); red16(q1);
        #pragma unroll
        for (int r = 0; r < 4; ++r) {
            float m0 = s0[r]*0.0625f;
            float i0 = __builtin_amdgcn_rsqf(fmaf(q0[r], 0.0625f, fmaf(m0, -m0, 1e-5f)));
            hln0[r] = (hn0[r] - m0)*i0*e1.x + e1.y;
            sm[HRB + (tok0 + r)*HRS + c] = f2bs(hln0[r]);
            float m1 = s1[r]*0.0625f;
            float i1 = __builtin_amdgcn_rsqf(fmaf(q1[r], 0.0625f, fmaf(m1, -m1, 1e-5f)));
            hln1[r] = (hn1[r] - m1)*i1*e1.x + e1.y;
            sm[HALF + HRB + (tok0 + r)*HRS + c] = f2bs(hln1[r]);
        }
    }
    LDS_ORDER();

    // ---- FFN: lin1(+bias,relu) -> lin2 (hln folded into C), both ----
    v4f o20, o21;
    {
        v8bf aA = *(const v8bf*)&sm[HRB + myrow*HRS + g*8];
        v8bf aB = *(const v8bf*)&sm[HALF + HRB + myrow*HRS + g*8];
        v8bf Bl10 = wf[6*64 + lane], Bl11 = wf[7*64 + lane];
        v4f f00 = MFMA(aA, Bl10, zacc);
        v4f f01 = MFMA(aA, Bl11, zacc);
        v4f f10 = MFMA(aB, Bl10, zacc);
        v4f f11 = MFMA(aB, Bl11, zacc);
        float4 e1 = ep4[c*4 + 1];
        #pragma unroll
        for (int r = 0; r < 4; ++r) {
            int tok = tok0 + r;
            sm[HRB + tok*HRS + c]             = f2bs(fmaxf(f00[r] + e1.z, 0.f));
            sm[HRB + tok*HRS + 16 + c]        = f2bs(fmaxf(f01[r] + e1.w, 0.f));
            sm[HALF + HRB + tok*HRS + c]      = f2bs(fmaxf(f10[r] + e1.z, 0.f));
            sm[HALF + HRB + tok*HRS + 16 + c] = f2bs(fmaxf(f11[r] + e1.w, 0.f));
        }
        LDS_ORDER();
        v8bf Bl2 = wf[8*64 + lane];
        v8bf a2A = *(const v8bf*)&sm[HRB + myrow*HRS + g*8];
        v8bf a2B = *(const v8bf*)&sm[HALF + HRB + myrow*HRS + g*8];
        o20 = MFMA(a2A, Bl2, hln0);
        o21 = MFMA(a2B, Bl2, hln1);
    }

    // ---- +lin2_b, LN2 (DPP), head dot; both batches ----
    float part0 = 0.f, part1 = 0.f;
    {
        float4 e2 = ep4[c*4 + 2];
        v4f hn0, s0, q0, hn1, s1, q1;
        #pragma unroll
        for (int r = 0; r < 4; ++r) {
            hn0[r] = o20[r] + e2.x; s0[r] = hn0[r]; q0[r] = hn0[r]*hn0[r];
            hn1[r] = o21[r] + e2.x; s1[r] = hn1[r]; q1[r] = hn1[r]*hn1[r];
        }
        red16(s0); red16(q0); red16(s1); red16(q1);
        #pragma unroll
        for (int r = 0; r < 4; ++r) {
            float m0 = s0[r]*0.0625f;
            float i0 = __builtin_amdgcn_rsqf(fmaf(q0[r], 0.0625f, fmaf(m0, -m0, 1e-5f)));
            part0 = fmaf((hn0[r] - m0)*i0*e2.y + e2.z, e2.w, part0);
            float m1 = s1[r]*0.0625f;
            float i1 = __builtin_amdgcn_rsqf(fmaf(q1[r], 0.0625f, fmaf(m1, -m1, 1e-5f)));
            part1 = fmaf((hn1[r] - m1)*i1*e2.y + e2.z, e2.w, part1);
        }
    }
    // 64-lane sums: DPP within 16, xor16, cross-32; two independent chains
    part0 = dppadd<0xB1>(part0);  part1 = dppadd<0xB1>(part1);
    part0 = dppadd<0x4E>(part0);  part1 = dppadd<0x4E>(part1);
    part0 = dppadd<0x124>(part0); part1 = dppadd<0x124>(part1);
    part0 = dppadd<0x128>(part0); part1 = dppadd<0x128>(part1);
    part0 += swz<0x401F>(part0);  part1 += swz<0x401F>(part1);
    part0 += __shfl_xor(part0, 32, 64);
    part1 += __shfl_xor(part1, 32, 64);
    float* fr0 = (float*)&sm[RED];
    float* fr1 = (float*)&sm[HALF + RED];
    if (lane == 0) { fr0[w] = part0; fr1[w] = part1; }
    __syncthreads();
    if (tid < 2) {
        const float* fr = (tid == 0) ? fr0 : fr1;
        out[b0 + tid] = (fr[0] + fr[1] + fr[2] + fr[3]) * (1.f/64.f) + head_b[0];
    }
}

extern "C" void kernel_launch(void* const* d_in, const int* in_sizes, int n_in,
                              void* d_out, int out_size, void* d_ws, size_t ws_size,
                              hipStream_t stream) {
    const float* x         = (const float*)d_in[0];
    const float* proj_w    = (const float*)d_in[1];
    const float* proj_b    = (const float*)d_in[2];
    const float* pos       = (const float*)d_in[3];
    const float* in_proj_w = (const float*)d_in[4];
    const float* in_proj_b = (const float*)d_in[5];
    const float* out_w     = (const float*)d_in[6];
    const float* out_b     = (const float*)d_in[7];
    const float* ln1_g     = (const float*)d_in[8];
    const float* ln1_b     = (const float*)d_in[9];
    const float* lin1_w    = (const float*)d_in[10];
    const float* lin1_b    = (const float*)d_in[11];
    const float* lin2_w    = (const float*)d_in[12];
    const float* lin2_b    = (const float*)d_in[13];
    const float* ln2_g     = (const float*)d_in[14];
    const float* ln2_b     = (const float*)d_in[15];
    const float* head_w    = (const float*)d_in[16];
    const float* head_b    = (const float*)d_in[17];
    float* ws = (float*)d_ws;

    tx_prep<<<1, 256, 0, stream>>>(proj_w, proj_b, pos, in_proj_w, in_proj_b,
                                   out_w, out_b, ln1_g, ln1_b, lin1_w, lin1_b,
                                   lin2_w, lin2_b, ln2_g, ln2_b, head_w, ws);
    tx_main<<<8192, 256, 0, stream>>>(x, ws, head_b, (float*)d_out);
}

// Round 9
// 315.739 us; speedup vs baseline: 1.2095x; 1.0091x over previous
//
#include <hip/hip_runtime.h>

// TxModel: B=16384, K=64 tokens, DIN=49, D=16, NH=2, HD=8, FF=32
// R13: R12 (dual-batch, sequential attention) with the occupancy cap fixed:
// LDS 21024B allows 7 blocks/CU but R12 said launch_bounds(256,6). -> (256,7)
// (+17% wave supply; VGPR cap 512/7=73 >= measured 40, no spill risk).
// R12 post-mortem: dual-batch logic verified correct+spill-free, neutral vs
// R10 only because 6<8 blocks/CU cancelled the shared-load savings.
// Carried: sequential attention (caps live VGPRs), R10 DPP rotate-reduce LNs,
// R8 global->register x + single barrier, R7 in-register P via swapped scores
// + slot-permuted V, folded biases in MFMA C-inputs, k pre-scaled,
// rcp/exp2/rsq natives, E[x^2]-E[x]^2 LNs.

#define SCALE 0.510069729f   // log2(e)/sqrt(8)

// LDS layout per batch half (short indices), HALF = 5256 shorts:
//   KR  [64][24] bf16 k rows (cols 16..23 zeroed)  [0,1536)
//   VTB [16][72] bf16 v^T, slot-permuted           [1536,2688)
//   HR  [64][40] bf16 h/q/ctx/hln/ff rows          [2688,5248)
//   RED 4 floats                                   [5248,5256)
#define KRS   24
#define VTB   1536
#define VTS   72
#define HRB   2688
#define HRS   40
#define RED   5248
#define HALF  5256
#define SMTOT 10512   // 21024 B -> 7 blocks/CU

// ws layout (floats): [0,2304) 9 weight B-frags (v8bf: frag*64+lane)
//                     [2304,3328) hbias [w][lane][r] = proj_b[c]+pos[tok][c]
//                     [3328,3584) epil  [c][16]   (ep[1] pre-scaled by SCALE)
#define WS_HB   2304
#define WS_EP   3328

typedef __bf16 v8bf __attribute__((ext_vector_type(8)));
typedef float  v4f  __attribute__((ext_vector_type(4)));

#define LDS_ORDER() __asm__ volatile("" ::: "memory")

static __device__ __forceinline__ short f2bs(float f) {
    __bf16 h = (__bf16)f;
    return __builtin_bit_cast(short, h);
}
#define MFMA(a,b,c) __builtin_amdgcn_mfma_f32_16x16x32_bf16((a),(b),(c),0,0,0)

// ds_swizzle, compile-time pattern. BitMode offset=(xor<<10)|(or<<5)|and.
template<int IMM> static __device__ __forceinline__ float swz(float x) {
    return __builtin_bit_cast(float,
        __builtin_amdgcn_ds_swizzle(__builtin_bit_cast(int, x), IMM));
}

// DPP-fused add. CTRL: 0xB1=quad_perm xor1, 0x4E=quad_perm xor2,
// 0x124=row_ror:4, 0x128=row_ror:8.
template<int CTRL> static __device__ __forceinline__ float dppadd(float v) {
    int t = __builtin_amdgcn_update_dpp(0, __builtin_bit_cast(int, v),
                                        CTRL, 0xF, 0xF, true);
    return v + __builtin_bit_cast(float, t);
}

// Sum over the 16 lanes of each row: quad butterfly then rotate-reduce.
static __device__ __forceinline__ void red16(v4f& v) {
    #pragma unroll
    for (int r = 0; r < 4; ++r) v[r] = dppadd<0xB1>(v[r]);
    #pragma unroll
    for (int r = 0; r < 4; ++r) v[r] = dppadd<0x4E>(v[r]);
    #pragma unroll
    for (int r = 0; r < 4; ++r) v[r] = dppadd<0x124>(v[r]);
    #pragma unroll
    for (int r = 0; r < 4; ++r) v[r] = dppadd<0x128>(v[r]);
}

__global__ __launch_bounds__(256)
void tx_prep(const float* __restrict__ proj_w, const float* __restrict__ proj_b,
             const float* __restrict__ pos,
             const float* __restrict__ in_proj_w, const float* __restrict__ in_proj_b,
             const float* __restrict__ out_w, const float* __restrict__ out_b,
             const float* __restrict__ ln1_g, const float* __restrict__ ln1_b,
             const float* __restrict__ lin1_w, const float* __restrict__ lin1_b,
             const float* __restrict__ lin2_w, const float* __restrict__ lin2_b,
             const float* __restrict__ ln2_g, const float* __restrict__ ln2_b,
             const float* __restrict__ head_w, float* __restrict__ ws)
{
    const int tid = threadIdx.x;
    const int wv = tid >> 6, lane = tid & 63;
    const int g = lane >> 4, c = lane & 15;
    v8bf* wf = (v8bf*)ws;
    v8bf F;
    if (wv == 0) {
        #pragma unroll
        for (int j = 0; j < 8; ++j) F[j] = (__bf16)proj_w[c*49 + g*8 + j];
        wf[0*64 + lane] = F;
        // remapped K-chunk2: g=0 -> k=32+j; g=1 -> k=40+j; g=2 -> only j==7
        // live (k=48); g=3 -> dead (A side loads col min(32+g*8,41)).
        #pragma unroll
        for (int j = 0; j < 8; ++j) {
            int k = (g == 0) ? (32 + j) : (g == 1) ? (40 + j)
                  : (g == 2 && j == 7) ? 48 : -1;
            F[j] = (k >= 0) ? (__bf16)proj_w[c*49 + k] : (__bf16)0.f;
        }
        wf[1*64 + lane] = F;
        #pragma unroll
        for (int nt = 0; nt < 3; ++nt) {
            #pragma unroll
            for (int j = 0; j < 8; ++j) { int k = g*8 + j; F[j] = (k < 16) ? (__bf16)in_proj_w[(nt*16 + c)*16 + k] : (__bf16)0.f; }
            wf[(2 + nt)*64 + lane] = F;
        }
    } else if (wv == 1) {
        #pragma unroll
        for (int j = 0; j < 8; ++j) { int k = g*8 + j; F[j] = (k < 16) ? (__bf16)out_w[c*16 + k] : (__bf16)0.f; }
        wf[5*64 + lane] = F;
        #pragma unroll
        for (int nt = 0; nt < 2; ++nt) {
            #pragma unroll
            for (int j = 0; j < 8; ++j) { int k = g*8 + j; F[j] = (k < 16) ? (__bf16)lin1_w[(nt*16 + c)*16 + k] : (__bf16)0.f; }
            wf[(6 + nt)*64 + lane] = F;
        }
        #pragma unroll
        for (int j = 0; j < 8; ++j) F[j] = (__bf16)lin2_w[c*32 + g*8 + j];
        wf[8*64 + lane] = F;
        if (lane < 16) {
            float* ep = ws + WS_EP + lane*16;
            ep[0]  = in_proj_b[lane];              // q bias
            ep[1]  = in_proj_b[16 + lane] * SCALE; // k bias, pre-scaled
            ep[2]  = in_proj_b[32 + lane];         // v bias
            ep[3]  = out_b[lane];
            ep[4]  = ln1_g[lane];
            ep[5]  = ln1_b[lane];
            ep[6]  = lin1_b[lane];
            ep[7]  = lin1_b[16 + lane];
            ep[8]  = lin2_b[lane];
            ep[9]  = ln2_g[lane];
            ep[10] = ln2_b[lane];
            ep[11] = head_w[lane];
            ep[12] = 0.f; ep[13] = 0.f; ep[14] = 0.f; ep[15] = 0.f;
        }
    } else {
        // hbias: [w][lane][r]; waves 2,3 take ww = {0,1} / {2,3}
        float* hb = ws + WS_HB;
        const int w0 = (wv - 2) * 2;
        #pragma unroll
        for (int i = 0; i < 2; ++i) {
            int ww = w0 + i;
            #pragma unroll
            for (int r = 0; r < 4; ++r)
                hb[ww*256 + lane*4 + r] = proj_b[c] + pos[(ww*16 + g*4 + r)*16 + c];
        }
    }
}

__global__ __launch_bounds__(256, 7)
void tx_main(const float* __restrict__ x, const float* __restrict__ ws,
             const float* __restrict__ head_b, float* __restrict__ out)
{
    __shared__ __align__(16) short sm[SMTOT];
    const int tid   = threadIdx.x;
    const int w     = tid >> 6;
    const int lane  = tid & 63;
    const int g     = lane >> 4;
    const int c     = lane & 15;
    const int b0    = blockIdx.x * 2;
    const int myrow = w*16 + c;
    const int tok0  = w*16 + g*4;
    const v8bf* wf  = (const v8bf*)ws;
    const float4* ep4 = (const float4*)(ws + WS_EP);

    v8bf zfrag;
    #pragma unroll
    for (int j = 0; j < 8; ++j) zfrag[j] = (__bf16)0.f;
    const v4f zacc = {0.f, 0.f, 0.f, 0.f};

    // ---- zero pads, both halves ----
    *(unsigned long long*)&sm[HRB + myrow*HRS + 16 + g*4] = 0ull;
    *(unsigned long long*)&sm[HALF + HRB + myrow*HRS + 16 + g*4] = 0ull;
    if (lane < 16) {
        float4 z4 = {0.f, 0.f, 0.f, 0.f};
        *(float4*)&sm[(w*16 + lane)*KRS + 16] = z4;
        *(float4*)&sm[HALF + (w*16 + lane)*KRS + 16] = z4;
    }

    // ---- proj: h = x @ proj_w^T, x global->register, both batches ----
    v4f hC0, hC1;
    {
        const float* xr0 = x + (size_t)b0 * 3136 + myrow*49;
        const float* xr1 = xr0 + 3136;
        const int off1 = (g < 2) ? (32 + g*8) : 41;   // bounds-safe chunk2
        v8bf a00, a01, a10, a11;
        #pragma unroll
        for (int j = 0; j < 8; ++j) a00[j] = (__bf16)xr0[g*8 + j];
        #pragma unroll
        for (int j = 0; j < 8; ++j) a01[j] = (__bf16)xr0[off1 + j];
        #pragma unroll
        for (int j = 0; j < 8; ++j) a10[j] = (__bf16)xr1[g*8 + j];
        #pragma unroll
        for (int j = 0; j < 8; ++j) a11[j] = (__bf16)xr1[off1 + j];
        v4f hb = ((const v4f*)(ws + WS_HB))[w*64 + lane];   // shared
        v8bf Bp0 = wf[0*64 + lane], Bp1 = wf[1*64 + lane];  // shared
        hC0 = MFMA(a00, Bp0, hb);
        hC1 = MFMA(a10, Bp0, hb);
        hC0 = MFMA(a01, Bp1, hC0);
        hC1 = MFMA(a11, Bp1, hC1);
        #pragma unroll
        for (int r = 0; r < 4; ++r) {
            sm[HRB + (tok0 + r)*HRS + c]        = f2bs(hC0[r]);
            sm[HALF + HRB + (tok0 + r)*HRS + c] = f2bs(hC1[r]);
        }
    }
    LDS_ORDER();   // h write -> qkv read is wave-local

    // ---- qkv = h @ in_proj_w^T + b; v SLOT-PERMUTED; both batches ----
    {
        v8bf aA = *(const v8bf*)&sm[HRB + myrow*HRS + g*8];
        v8bf aB = *(const v8bf*)&sm[HALF + HRB + myrow*HRS + g*8];
        v8bf Bq0 = wf[2*64 + lane], Bq1 = wf[3*64 + lane], Bq2 = wf[4*64 + lane];
        v4f qC0 = MFMA(aA, Bq0, zacc);
        v4f qC1 = MFMA(aB, Bq0, zacc);
        v4f kC0 = MFMA(aA, Bq1, zacc);
        v4f kC1 = MFMA(aB, Bq1, zacc);
        v4f vC0 = MFMA(aA, Bq2, zacc);
        v4f vC1 = MFMA(aB, Bq2, zacc);
        float4 e0 = ep4[c*4];
        const int vsl = VTB + c*VTS + 32*(w >> 1) + 8*g + 4*(w & 1);
        #pragma unroll
        for (int r = 0; r < 4; ++r) {
            int tok = tok0 + r;
            sm[HRB + tok*HRS + c]        = f2bs(qC0[r] + e0.x);
            sm[HALF + HRB + tok*HRS + c] = f2bs(qC1[r] + e0.x);
            sm[tok*KRS + c]              = f2bs(fmaf(kC0[r], SCALE, e0.y));
            sm[HALF + tok*KRS + c]       = f2bs(fmaf(kC1[r], SCALE, e0.y));
            sm[vsl + r]                  = f2bs(vC0[r] + e0.z);
            sm[HALF + vsl + r]           = f2bs(vC1[r] + e0.z);
        }
    }
    __syncthreads();   // the ONE barrier: k/V/KR-zero cross-wave visibility

    // ---- attention, SEQUENTIAL per batch (caps live VGPRs; R11 spilled) ----
    #pragma unroll
    for (int bb = 0; bb < 2; ++bb) {
        const int B = bb ? HALF : 0;
        v4f ctxA, ctxB;   // head0 / head1
        {
            v8bf aq = *(const v8bf*)&sm[B + HRB + myrow*HRS + g*8];
            v8bf k0 = *(const v8bf*)&sm[B + (0*16 + c)*KRS + g*8];
            v8bf k1 = *(const v8bf*)&sm[B + (1*16 + c)*KRS + g*8];
            v8bf k2 = *(const v8bf*)&sm[B + (2*16 + c)*KRS + g*8];
            v8bf k3 = *(const v8bf*)&sm[B + (3*16 + c)*KRS + g*8];
            #pragma unroll
            for (int hh = 0; hh < 2; ++hh) {
                v8bf bq = (g == hh) ? aq : zfrag;
                v8bf plo, phi;
                {
                    v4f s0 = MFMA(k0, bq, zacc);
                    v4f s1 = MFMA(k1, bq, zacc);
                    #pragma unroll
                    for (int r = 0; r < 4; ++r) {
                        plo[r]     = (__bf16)__builtin_amdgcn_exp2f(s0[r]);
                        plo[4 + r] = (__bf16)__builtin_amdgcn_exp2f(s1[r]);
                    }
                    v4f s2 = MFMA(k2, bq, zacc);
                    v4f s3 = MFMA(k3, bq, zacc);
                    #pragma unroll
                    for (int r = 0; r < 4; ++r) {
                        phi[r]     = (__bf16)__builtin_amdgcn_exp2f(s2[r]);
                        phi[4 + r] = (__bf16)__builtin_amdgcn_exp2f(s3[r]);
                    }
                }
                // V (slot-permuted) + ones column for softmax denominator
                v8bf bv0 = zfrag, bv1 = zfrag;
                bool act  = (hh == 0) ? (c < 8) : (c >= 8);
                int  onec = (hh == 0) ? 8 : 7;
                if (act) {
                    bv0 = *(const v8bf*)&sm[B + VTB + c*VTS + g*8];
                    bv1 = *(const v8bf*)&sm[B + VTB + c*VTS + 32 + g*8];
                } else if (c == onec) {
                    #pragma unroll
                    for (int j = 0; j < 8; ++j) { bv0[j] = (__bf16)1.f; bv1[j] = (__bf16)1.f; }
                }
                v4f acc = MFMA(plo, bv0, zacc);
                acc = MFMA(phi, bv1, acc);
                if (hh) ctxB = acc; else ctxA = acc;
            }
        }
        // softmax normalize (l broadcast via ds_swizzle; v_rcp not div)
        #pragma unroll
        for (int r = 0; r < 4; ++r) {
            float l0 = swz<0x110>(ctxA[r]);   // from lane (lane&48)|8
            float l1 = swz<0x0F0>(ctxB[r]);   // from lane (lane&48)|7
            float num = (c < 8) ? ctxA[r] : ctxB[r];
            float den = (c < 8) ? l0 : l1;
            sm[B + HRB + (tok0 + r)*HRS + c] = f2bs(num * __builtin_amdgcn_rcpf(den));
        }
    }
    LDS_ORDER();

    // ---- out-proj (+hC via C-input) + LN1 (DPP reduce), both batches ----
    v4f hln0, hln1;
    {
        v8bf aA = *(const v8bf*)&sm[HRB + myrow*HRS + g*8];
        v8bf aB = *(const v8bf*)&sm[HALF + HRB + myrow*HRS + g*8];
        v8bf Bo = wf[5*64 + lane];
        v4f oC0 = MFMA(aA, Bo, hC0);
        v4f oC1 = MFMA(aB, Bo, hC1);
        float4 e0 = ep4[c*4];
        float4 e1 = ep4[c*4 + 1];
        v4f hn0, s0, q0, hn1, s1, q1;
        #pragma unroll
        for (int r = 0; r < 4; ++r) {
            hn0[r] = oC0[r] + e0.w; s0[r] = hn0[r]; q0[r] = hn0[r]*hn0[r];
            hn1[r] = oC1[r] + e0.w; s1[r] = hn1[r]; q1[r] = hn1[r]*hn1[r];
        }
        red16(s0); red16(q0); red16(s1); red16(q1);
        #pragma unroll
        for (int r = 0; r < 4; ++r) {
            float m0 = s0[r]*0.0625f;
            float i0 = __builtin_amdgcn_rsqf(fmaf(q0[r], 0.0625f, fmaf(m0, -m0, 1e-5f)));
            hln0[r] = (hn0[r] - m0)*i0*e1.x + e1.y;
            sm[HRB + (tok0 + r)*HRS + c] = f2bs(hln0[r]);
            float m1 = s1[r]*0.0625f;
            float i1 = __builtin_amdgcn_rsqf(fmaf(q1[r], 0.0625f, fmaf(m1, -m1, 1e-5f)));
            hln1[r] = (hn1[r] - m1)*i1*e1.x + e1.y;
            sm[HALF + HRB + (tok0 + r)*HRS + c] = f2bs(hln1[r]);
        }
    }
    LDS_ORDER();

    // ---- FFN: lin1(+bias,relu) -> lin2 (hln folded into C), both ----
    v4f o20, o21;
    {
        v8bf aA = *(const v8bf*)&sm[HRB + myrow*HRS + g*8];
        v8bf aB = *(const v8bf*)&sm[HALF + HRB + myrow*HRS + g*8];
        v8bf Bl10 = wf[6*64 + lane], Bl11 = wf[7*64 + lane];
        v4f f00 = MFMA(aA, Bl10, zacc);
        v4f f01 = MFMA(aA, Bl11, zacc);
        v4f f10 = MFMA(aB, Bl10, zacc);
        v4f f11 = MFMA(aB, Bl11, zacc);
        float4 e1 = ep4[c*4 + 1];
        #pragma unroll
        for (int r = 0; r < 4; ++r) {
            int tok = tok0 + r;
            sm[HRB + tok*HRS + c]             = f2bs(fmaxf(f00[r] + e1.z, 0.f));
            sm[HRB + tok*HRS + 16 + c]        = f2bs(fmaxf(f01[r] + e1.w, 0.f));
            sm[HALF + HRB + tok*HRS + c]      = f2bs(fmaxf(f10[r] + e1.z, 0.f));
            sm[HALF + HRB + tok*HRS + 16 + c] = f2bs(fmaxf(f11[r] + e1.w, 0.f));
        }
        LDS_ORDER();
        v8bf Bl2 = wf[8*64 + lane];
        v8bf a2A = *(const v8bf*)&sm[HRB + myrow*HRS + g*8];
        v8bf a2B = *(const v8bf*)&sm[HALF + HRB + myrow*HRS + g*8];
        o20 = MFMA(a2A, Bl2, hln0);
        o21 = MFMA(a2B, Bl2, hln1);
    }

    // ---- +lin2_b, LN2 (DPP), head dot; both batches ----
    float part0 = 0.f, part1 = 0.f;
    {
        float4 e2 = ep4[c*4 + 2];
        v4f hn0, s0, q0, hn1, s1, q1;
        #pragma unroll
        for (int r = 0; r < 4; ++r) {
            hn0[r] = o20[r] + e2.x; s0[r] = hn0[r]; q0[r] = hn0[r]*hn0[r];
            hn1[r] = o21[r] + e2.x; s1[r] = hn1[r]; q1[r] = hn1[r]*hn1[r];
        }
        red16(s0); red16(q0); red16(s1); red16(q1);
        #pragma unroll
        for (int r = 0; r < 4; ++r) {
            float m0 = s0[r]*0.0625f;
            float i0 = __builtin_amdgcn_rsqf(fmaf(q0[r], 0.0625f, fmaf(m0, -m0, 1e-5f)));
            part0 = fmaf((hn0[r] - m0)*i0*e2.y + e2.z, e2.w, part0);
            float m1 = s1[r]*0.0625f;
            float i1 = __builtin_amdgcn_rsqf(fmaf(q1[r], 0.0625f, fmaf(m1, -m1, 1e-5f)));
            part1 = fmaf((hn1[r] - m1)*i1*e2.y + e2.z, e2.w, part1);
        }
    }
    // 64-lane sums: DPP within 16, xor16, cross-32; two independent chains
    part0 = dppadd<0xB1>(part0);  part1 = dppadd<0xB1>(part1);
    part0 = dppadd<0x4E>(part0);  part1 = dppadd<0x4E>(part1);
    part0 = dppadd<0x124>(part0); part1 = dppadd<0x124>(part1);
    part0 = dppadd<0x128>(part0); part1 = dppadd<0x128>(part1);
    part0 += swz<0x401F>(part0);  part1 += swz<0x401F>(part1);
    part0 += __shfl_xor(part0, 32, 64);
    part1 += __shfl_xor(part1, 32, 64);
    float* fr0 = (float*)&sm[RED];
    float* fr1 = (float*)&sm[HALF + RED];
    if (lane == 0) { fr0[w] = part0; fr1[w] = part1; }
    __syncthreads();
    if (tid < 2) {
        const float* fr = (tid == 0) ? fr0 : fr1;
        out[b0 + tid] = (fr[0] + fr[1] + fr[2] + fr[3]) * (1.f/64.f) + head_b[0];
    }
}

extern "C" void kernel_launch(void* const* d_in, const int* in_sizes, int n_in,
                              void* d_out, int out_size, void* d_ws, size_t ws_size,
                              hipStream_t stream) {
    const float* x         = (const float*)d_in[0];
    const float* proj_w    = (const float*)d_in[1];
    const float* proj_b    = (const float*)d_in[2];
    const float* pos       = (const float*)d_in[3];
    const float* in_proj_w = (const float*)d_in[4];
    const float* in_proj_b = (const float*)d_in[5];
    const float* out_w     = (const float*)d_in[6];
    const float* out_b     = (const float*)d_in[7];
    const float* ln1_g     = (const float*)d_in[8];
    const float* ln1_b     = (const float*)d_in[9];
    const float* lin1_w    = (const float*)d_in[10];
    const float* lin1_b    = (const float*)d_in[11];
    const float* lin2_w    = (const float*)d_in[12];
    const float* lin2_b    = (const float*)d_in[13];
    const float* ln2_g     = (const float*)d_in[14];
    const float* ln2_b     = (const float*)d_in[15];
    const float* head_w    = (const float*)d_in[16];
    const float* head_b    = (const float*)d_in[17];
    float* ws = (float*)d_ws;

    tx_prep<<<1, 256, 0, stream>>>(proj_w, proj_b, pos, in_proj_w, in_proj_b,
                                   out_w, out_b, ln1_g, ln1_b, lin1_w, lin1_b,
                                   lin2_w, lin2_b, ln2_g, ln2_b, head_w, ws);
    tx_main<<<8192, 256, 0, stream>>>(x, ws, head_b, (float*)d_out);
}